// Round 1
// baseline (11.891 us; speedup 1.0000x reference)
//
#include <hip/hip_runtime.h>

#define BATCH 4096
#define NCLS  1024
#define DEPTH 10

// One wave (64 lanes) per sample. Lane l holds elements [l*16, l*16+16) of the
// row. Aligned block sums along target's root path:
//   S[0..4]  : within the owning lane's 16-element segment (t is wave-uniform,
//              so the selects are uniform and every lane computes "its" path;
//              only lane t>>4 has the real data).
//   S[5..10] : butterfly __shfl_xor over lanes; after step k each lane holds
//              the sum of its aligned 2^(k+1)-lane group, so lane t>>4 carries
//              the correct values at every level.
__global__ __launch_bounds__(256) void hll_per_sample(
    const float* __restrict__ inputs,
    const int*   __restrict__ target,
    const float* __restrict__ weights,
    float*       __restrict__ per_sample)
{
    const int wave = threadIdx.x >> 6;
    const int lane = threadIdx.x & 63;
    const int b = blockIdx.x * 4 + wave;

    const int t = target[b];                       // wave-uniform
    const float4* row = reinterpret_cast<const float4*>(inputs + (size_t)b * NCLS);

    float4 x0 = row[lane * 4 + 0];
    float4 x1 = row[lane * 4 + 1];
    float4 x2 = row[lane * 4 + 2];
    float4 x3 = row[lane * 4 + 3];

    const int s = t & 15;        // position within 16-elem segment (uniform)
    const int q = s >> 2;        // which float4
    const int r = s & 3;         // which component

    float4 xq = (q == 0) ? x0 : (q == 1) ? x1 : (q == 2) ? x2 : x3;

    float S[DEPTH + 1];
    S[0] = (r == 0) ? xq.x : (r == 1) ? xq.y : (r == 2) ? xq.z : xq.w;
    S[1] = (r < 2) ? (xq.x + xq.y) : (xq.z + xq.w);
    S[2] = xq.x + xq.y + xq.z + xq.w;

    const float q0 = x0.x + x0.y + x0.z + x0.w;
    const float q1 = x1.x + x1.y + x1.z + x1.w;
    const float q2 = x2.x + x2.y + x2.z + x2.w;
    const float q3 = x3.x + x3.y + x3.z + x3.w;
    S[3] = (q < 2) ? (q0 + q1) : (q2 + q3);
    S[4] = q0 + q1 + q2 + q3;

    float ssum = S[4];
    #pragma unroll
    for (int k = 0; k < 6; ++k) {
        ssum += __shfl_xor(ssum, 1 << k, 64);
        S[5 + k] = ssum;
    }

    // weights[t, :] — uniform address, 10 floats (exp(-j/2), but read the real data)
    const float* w = weights + (size_t)t * DEPTH;

    float acc = 0.0f;
    #pragma unroll
    for (int j = 0; j < DEPTH; ++j) {
        const float num = S[j];
        const float den = S[j + 1];
        // reference: where num==0, val = num (== 0); else -log(num/den)
        const float val = (num != 0.0f) ? -__logf(num / den) : num;
        acc += w[j] * val;
    }

    if (lane == (t >> 4)) per_sample[b] = acc;
}

// Deterministic single-block mean over BATCH per-sample losses.
__global__ __launch_bounds__(256) void hll_reduce(
    const float* __restrict__ per_sample,
    float*       __restrict__ out)
{
    __shared__ float lds[256];
    const int tid = threadIdx.x;
    float s = 0.0f;
    #pragma unroll
    for (int i = 0; i < BATCH / 256; ++i)
        s += per_sample[tid + i * 256];
    lds[tid] = s;
    __syncthreads();
    #pragma unroll
    for (int off = 128; off > 0; off >>= 1) {
        if (tid < off) lds[tid] += lds[tid + off];
        __syncthreads();
    }
    if (tid == 0) out[0] = lds[0] * (1.0f / (float)BATCH);
}

extern "C" void kernel_launch(void* const* d_in, const int* in_sizes, int n_in,
                              void* d_out, int out_size, void* d_ws, size_t ws_size,
                              hipStream_t stream) {
    const float* inputs  = (const float*)d_in[0];
    const int*   target  = (const int*)d_in[1];
    // d_in[2] = onehot_num, d_in[3] = onehot_den: structural, not needed.
    const float* weights = (const float*)d_in[4];

    float* ws_per_sample = (float*)d_ws;   // BATCH floats
    float* out = (float*)d_out;

    hll_per_sample<<<BATCH / 4, 256, 0, stream>>>(inputs, target, weights, ws_per_sample);
    hll_reduce<<<1, 256, 0, stream>>>(ws_per_sample, out);
}